// Round 2
// baseline (1617.590 us; speedup 1.0000x reference)
//
#include <hip/hip_runtime.h>

#define N_NODES 100000
#define N_EDGES 1600000
#define HID 64
#define EDIM 32
#define BN_EPS 1e-5f

#define SCAN_CHUNK 1024
#define NB_SCAN ((N_NODES + SCAN_CHUNK - 1) / SCAN_CHUNK)   // 98

#define G_NODES 16                       // dst nodes per block (gather)

typedef __attribute__((ext_vector_type(16))) float f32x16;

// ---------------------------------------------------------------------------
// Counting sort of edges by dst.  Built once per call, reused by all 3 layers.
// ---------------------------------------------------------------------------
__global__ __launch_bounds__(256) void hist_kernel(
    const int* __restrict__ dst, int* __restrict__ cnt)
{
    int i = (int)(blockIdx.x * blockDim.x + threadIdx.x);
    const int stride = (int)(gridDim.x * blockDim.x);
    for (; i < N_EDGES; i += stride) atomicAdd(&cnt[dst[i]], 1);
}

__global__ __launch_bounds__(256) void scan1_kernel(
    const int* __restrict__ cnt, int* __restrict__ bsum)
{
    __shared__ int s[256];
    const int b = (int)blockIdx.x, t = (int)threadIdx.x;
    const int base = b * SCAN_CHUNK + t * 4;
    int sum = 0;
#pragma unroll
    for (int k = 0; k < 4; ++k) {
        int idx = base + k;
        if (idx < N_NODES) sum += cnt[idx];
    }
    s[t] = sum;
    __syncthreads();
    for (int off = 128; off > 0; off >>= 1) {
        if (t < off) s[t] += s[t + off];
        __syncthreads();
    }
    if (t == 0) bsum[b] = s[0];
}

__global__ __launch_bounds__(128) void scan2_kernel(
    const int* __restrict__ bsum, int* __restrict__ bofs, int* __restrict__ row_ptr)
{
    __shared__ int s[128];
    const int t = (int)threadIdx.x;
    const int v = (t < NB_SCAN) ? bsum[t] : 0;
    s[t] = v;
    __syncthreads();
    for (int off = 1; off < 128; off <<= 1) {
        int add = (t >= off) ? s[t - off] : 0;
        __syncthreads();
        s[t] += add;
        __syncthreads();
    }
    if (t < NB_SCAN) bofs[t] = s[t] - v;
    if (t == NB_SCAN - 1) row_ptr[N_NODES] = s[t];
}

__global__ __launch_bounds__(256) void scan3_kernel(
    const int* __restrict__ cnt, const int* __restrict__ bofs,
    int* __restrict__ row_ptr, int* __restrict__ pos)
{
    __shared__ int s[256];
    const int b = (int)blockIdx.x, t = (int)threadIdx.x;
    const int base = b * SCAN_CHUNK + t * 4;
    int v[4];
    int sum = 0;
#pragma unroll
    for (int k = 0; k < 4; ++k) {
        int idx = base + k;
        v[k] = (idx < N_NODES) ? cnt[idx] : 0;
        sum += v[k];
    }
    s[t] = sum;
    __syncthreads();
    for (int off = 1; off < 256; off <<= 1) {
        int add = (t >= off) ? s[t - off] : 0;
        __syncthreads();
        s[t] += add;
        __syncthreads();
    }
    int run = s[t] - sum + bofs[b];
#pragma unroll
    for (int k = 0; k < 4; ++k) {
        int idx = base + k;
        if (idx < N_NODES) {
            row_ptr[idx] = run;
            pos[idx] = run;
            run += v[k];
        }
    }
}

__global__ __launch_bounds__(256) void scatter_kernel(
    const int* __restrict__ src, const int* __restrict__ dst,
    int* __restrict__ pos, int* __restrict__ perm_e, int* __restrict__ perm_src)
{
    int i = (int)(blockIdx.x * blockDim.x + threadIdx.x);
    const int stride = (int)(gridDim.x * blockDim.x);
    for (; i < N_EDGES; i += stride) {
        const int d = dst[i];
        const int p = atomicAdd(&pos[d], 1);
        perm_e[p] = i;
        perm_src[p] = src[i];
    }
}

// ---------------------------------------------------------------------------
// Scalar-path gather.  Wave-uniform attr rows live in SGPRs (s_load_dwordx16):
// one 128 B fetch per wave per edge instead of an 8 KB LDS/L1 broadcast.
// FMA consumes the SGPR operand directly (v_fma s,v,v).  No LDS, no barriers.
// Manual lgkmcnt(0)+sched_barrier discipline per edge (depth-1 scalar
// pipeline; TLP hides the rest).  x-gather stays per-lane VMEM (compiler
// vmcnt) - no compiler LGKM ops exist in the loop so counts can't mix.
// ---------------------------------------------------------------------------
#define SWAIT() do { asm volatile("s_waitcnt lgkmcnt(0)" ::: "memory"); \
                     __builtin_amdgcn_sched_barrier(0); } while (0)

__device__ __forceinline__ float edge_step(
    int j, int FL,
    const float* __restrict__ eattr, const int* __restrict__ perm_e,
    const int* __restrict__ perm_src, const float* __restrict__ x,
    int lane, const float* __restrict__ wv, float bias,
    f32x16& cl, f32x16& ch,          // current attr row (arrives at SWAIT)
    f32x16& nl, f32x16& nh,          // next attr row destination
    int& eN, int& sN,                // in: perm_e[j+1], src[j+2]; out: j+2/j+3
    float& xq0, float& xq1)          // x rows for edges j, j+1
{
    SWAIT();                                          // cl/ch, eN, sN ready
    // issue next attr row (edge j+1) + scalar index stream (j+2 / j+3)
    const float* ap = eattr + (size_t)(unsigned)eN * EDIM;
    int j2 = j + 2; if (j2 > FL) j2 = FL;
    int j3 = j + 3; if (j3 > FL) j3 = FL;
    int e_out, s_out;
    asm volatile(
        "s_load_dwordx16 %0, %4, 0x0\n\t"
        "s_load_dwordx16 %1, %4, 0x40\n\t"
        "s_load_dword    %2, %5, 0x0\n\t"
        "s_load_dword    %3, %6, 0x0"
        : "=&s"(nl), "=&s"(nh), "=&s"(e_out), "=&s"(s_out)
        : "s"(ap), "s"(perm_e + j2), "s"(perm_src + j3));

    // per-lane x prefetch for edge j+2 (VMEM, compiler-managed vmcnt)
    const float xq2 = x[(size_t)(unsigned)sN * HID + lane];

    // e = bias + attr . We_col  via 4 independent FMA chains, SGPR attr
    float ee0 = bias, ee1 = 0.0f, ee2 = 0.0f, ee3 = 0.0f;
#pragma unroll
    for (int k = 0; k < 16; k += 4) {
        ee0 = fmaf(cl[k + 0], wv[k + 0], ee0);
        ee1 = fmaf(cl[k + 1], wv[k + 1], ee1);
        ee2 = fmaf(cl[k + 2], wv[k + 2], ee2);
        ee3 = fmaf(cl[k + 3], wv[k + 3], ee3);
    }
#pragma unroll
    for (int k = 0; k < 16; k += 4) {
        ee0 = fmaf(ch[k + 0], wv[16 + k + 0], ee0);
        ee1 = fmaf(ch[k + 1], wv[16 + k + 1], ee1);
        ee2 = fmaf(ch[k + 2], wv[16 + k + 2], ee2);
        ee3 = fmaf(ch[k + 3], wv[16 + k + 3], ee3);
    }
    const float c = fmaxf(xq0 + ((ee0 + ee1) + (ee2 + ee3)), 0.0f);
    xq0 = xq1; xq1 = xq2;
    eN = e_out; sN = s_out;
    return c;
}

__global__ __launch_bounds__(256, 6) void gather_csr_kernel(
    const float* __restrict__ x, const float* __restrict__ eattr,
    const int* __restrict__ row_ptr, const int* __restrict__ perm_e,
    const int* __restrict__ perm_src,
    const float* __restrict__ We, const float* __restrict__ be,
    float* __restrict__ agg)
{
    const int tid  = (int)threadIdx.x;
    const int lane = tid & 63;
    const int w    = __builtin_amdgcn_readfirstlane(tid >> 6);   // wave 0..3
    const int node_lo = (int)blockIdx.x * G_NODES + 4 * w;

    // this lane's weight column (reused for all edges of the wave)
    float wv[EDIM];
#pragma unroll
    for (int k = 0; k < EDIM; ++k) wv[k] = We[k * HID + lane];
    const float bias = be[lane];

    // this wave's 4 node ranges (forced into SGPRs)
    int rpv[5];
#pragma unroll
    for (int i = 0; i < 5; ++i) {
        int n = node_lo + i;
        n = (n < N_NODES) ? n : N_NODES;
        rpv[i] = __builtin_amdgcn_readfirstlane(row_ptr[n]);
    }
    const int F0 = rpv[0], rp1 = rpv[1], rp2 = rpv[2], rp3 = rpv[3], F1 = rpv[4];

    float a = 0.0f, sn1 = 0.0f, sn2 = 0.0f, sn3 = 0.0f;

    if (F0 < F1) {
        const int FL = F1 - 1;
        f32x16 A0, A1, B0, B1;
        int eN, sN;
        float xq0, xq1;

        // ---- prologue: prime scalar index stream + first attr row + x rows
        {
            int jB = F0 + 1; if (jB > FL) jB = FL;
            int jC = F0 + 2; if (jC > FL) jC = FL;
            int e0i, eNi, s0i, s1i, sNi;
            asm volatile(
                "s_load_dword %0, %5, 0x0\n\t"
                "s_load_dword %1, %6, 0x0\n\t"
                "s_load_dword %2, %7, 0x0\n\t"
                "s_load_dword %3, %8, 0x0\n\t"
                "s_load_dword %4, %9, 0x0"
                : "=&s"(e0i), "=&s"(eNi), "=&s"(s0i), "=&s"(s1i), "=&s"(sNi)
                : "s"(perm_e + F0), "s"(perm_e + jB), "s"(perm_src + F0),
                  "s"(perm_src + jB), "s"(perm_src + jC));
            SWAIT();
            const float* ap0 = eattr + (size_t)(unsigned)e0i * EDIM;
            asm volatile(
                "s_load_dwordx16 %0, %2, 0x0\n\t"
                "s_load_dwordx16 %1, %2, 0x40"
                : "=&s"(A0), "=&s"(A1) : "s"(ap0));
            xq0 = x[(size_t)(unsigned)s0i * HID + lane];
            xq1 = x[(size_t)(unsigned)s1i * HID + lane];
            eN = eNi; sN = sNi;
        }

        // ---- flat edge loop, ping-pong scalar buffers, snapshot boundaries
        int j = F0;
        while (true) {
            a += edge_step(j, FL, eattr, perm_e, perm_src, x, lane, wv, bias,
                           A0, A1, B0, B1, eN, sN, xq0, xq1);
            ++j;
            if (j == rp1) sn1 = a;
            if (j == rp2) sn2 = a;
            if (j == rp3) sn3 = a;
            if (j >= F1) break;

            a += edge_step(j, FL, eattr, perm_e, perm_src, x, lane, wv, bias,
                           B0, B1, A0, A1, eN, sN, xq0, xq1);
            ++j;
            if (j == rp1) sn1 = a;
            if (j == rp2) sn2 = a;
            if (j == rp3) sn3 = a;
            if (j >= F1) break;
        }
        SWAIT();   // drain the tail s_loads before epilogue / endpgm
    }

    // segment sums from running-sum snapshots (monotone relu stream)
    float r[4];
    r[0] = sn1;
    r[1] = sn2 - sn1;
    r[2] = sn3 - sn2;
    r[3] = a - sn3;
#pragma unroll
    for (int q = 0; q < 4; ++q) {
        const int n = node_lo + q;
        if (n < N_NODES) agg[(size_t)n * HID + lane] = r[q];
    }
}

// ---------------------------------------------------------------------------
// MLP kernel: lane = node.  u = relu((x+agg)@W1+b1)@W2+b2
// ---------------------------------------------------------------------------
__global__ __launch_bounds__(256) void mlp_kernel(
    const float* __restrict__ xin, const float* __restrict__ agg,
    const float* __restrict__ W1, const float* __restrict__ b1,
    const float* __restrict__ W2, const float* __restrict__ b2,
    float* __restrict__ uout)
{
    const int lane = threadIdx.x & 63;
    const int wid  = (int)((blockIdx.x * blockDim.x + threadIdx.x) >> 6);
    const int n    = wid * 64 + lane;
    const bool ok  = (n < N_NODES);
    const size_t base = (size_t)n * HID;

    float h[HID];
    if (ok) {
        const float4* px = (const float4*)(xin + base);
        const float4* pa = (const float4*)(agg + base);
#pragma unroll
        for (int j = 0; j < HID / 4; ++j) {
            float4 xv = px[j];
            float4 av = pa[j];
            h[4 * j + 0] = xv.x + av.x;
            h[4 * j + 1] = xv.y + av.y;
            h[4 * j + 2] = xv.z + av.z;
            h[4 * j + 3] = xv.w + av.w;
        }
    } else {
#pragma unroll
        for (int k = 0; k < HID; ++k) h[k] = 0.0f;
    }

    float u[HID];
#pragma unroll
    for (int f = 0; f < HID; ++f) u[f] = b2[f];

    for (int c = 0; c < 4; ++c) {
        float t[16];
#pragma unroll
        for (int j = 0; j < 16; ++j) t[j] = b1[c * 16 + j];
#pragma unroll
        for (int k = 0; k < HID; ++k) {
            const float hk = h[k];
#pragma unroll
            for (int j = 0; j < 16; ++j)
                t[j] = fmaf(hk, W1[k * HID + c * 16 + j], t[j]);
        }
#pragma unroll
        for (int j = 0; j < 16; ++j) t[j] = fmaxf(t[j], 0.0f);
#pragma unroll
        for (int j = 0; j < 16; ++j) {
            const float tj = t[j];
#pragma unroll
            for (int f = 0; f < HID; ++f)
                u[f] = fmaf(tj, W2[(c * 16 + j) * HID + f], u[f]);
        }
    }

    if (ok) {
        float4* po = (float4*)(uout + base);
#pragma unroll
        for (int j = 0; j < HID / 4; ++j)
            po[j] = make_float4(u[4 * j], u[4 * j + 1], u[4 * j + 2], u[4 * j + 3]);
    }
}

// ---------------------------------------------------------------------------
// Final projection: out = x @ Wout + bout
// ---------------------------------------------------------------------------
__global__ __launch_bounds__(256) void out_kernel(
    const float* __restrict__ xin, const float* __restrict__ Wo,
    const float* __restrict__ bo, float* __restrict__ out)
{
    const int lane = threadIdx.x & 63;
    const int wid  = (int)((blockIdx.x * blockDim.x + threadIdx.x) >> 6);
    const int n    = wid * 64 + lane;
    const bool ok  = (n < N_NODES);
    const size_t base = (size_t)n * HID;

    float h[HID];
    if (ok) {
        const float4* px = (const float4*)(xin + base);
#pragma unroll
        for (int j = 0; j < HID / 4; ++j) {
            float4 xv = px[j];
            h[4 * j + 0] = xv.x; h[4 * j + 1] = xv.y;
            h[4 * j + 2] = xv.z; h[4 * j + 3] = xv.w;
        }
    } else {
#pragma unroll
        for (int k = 0; k < HID; ++k) h[k] = 0.0f;
    }

    for (int c = 0; c < 4; ++c) {
        float t[16];
#pragma unroll
        for (int j = 0; j < 16; ++j) t[j] = bo[c * 16 + j];
#pragma unroll
        for (int k = 0; k < HID; ++k) {
            const float hk = h[k];
#pragma unroll
            for (int j = 0; j < 16; ++j)
                t[j] = fmaf(hk, Wo[k * HID + c * 16 + j], t[j]);
        }
        if (ok) {
            float4* po = (float4*)(out + base + c * 16);
#pragma unroll
            for (int j = 0; j < 4; ++j)
                po[j] = make_float4(t[4 * j], t[4 * j + 1], t[4 * j + 2], t[4 * j + 3]);
        }
    }
}

// ---------------------------------------------------------------------------
// BN statistics (sum / sumsq per feature)
// ---------------------------------------------------------------------------
__global__ __launch_bounds__(256) void stats_kernel(
    const float* __restrict__ u, float* __restrict__ stats)
{
    __shared__ float ls[256];
    __shared__ float ls2[256];
    const int tid = (int)threadIdx.x;
    const int g   = (int)(blockIdx.x * 256 + tid);
    const int f   = g & 63;
    const int row = g >> 6;
    const int rstride = (int)((gridDim.x * 256) >> 6);

    float s = 0.0f, s2 = 0.0f;
    for (int n = row; n < N_NODES; n += rstride) {
        float v = u[(size_t)n * HID + f];
        s += v;
        s2 = fmaf(v, v, s2);
    }
    ls[tid] = s;
    ls2[tid] = s2;
    __syncthreads();
    if (tid < 64) {
        float a = ls[tid] + ls[tid + 64] + ls[tid + 128] + ls[tid + 192];
        float b = ls2[tid] + ls2[tid + 64] + ls2[tid + 128] + ls2[tid + 192];
        atomicAdd(&stats[tid], a);
        atomicAdd(&stats[64 + tid], b);
    }
}

// ---------------------------------------------------------------------------
// BN apply + relu
// ---------------------------------------------------------------------------
__global__ __launch_bounds__(256) void bn_relu_kernel(
    const float* __restrict__ u, const float* __restrict__ stats,
    const float* __restrict__ gamma, const float* __restrict__ beta,
    float* __restrict__ xout)
{
    const int total4 = N_NODES * HID / 4;
    int i = (int)(blockIdx.x * blockDim.x + threadIdx.x);
    const int stride = (int)(gridDim.x * blockDim.x);
    const int fb = (i * 4) & 63;

    const float invN = 1.0f / (float)N_NODES;
    float sc[4], sh[4];
#pragma unroll
    for (int j = 0; j < 4; ++j) {
        float mean = stats[fb + j] * invN;
        float var  = stats[64 + fb + j] * invN - mean * mean;
        float s    = gamma[fb + j] * rsqrtf(var + BN_EPS);
        sc[j] = s;
        sh[j] = beta[fb + j] - mean * s;
    }
    for (; i < total4; i += stride) {
        float4 v = ((const float4*)u)[i];
        v.x = fmaxf(fmaf(v.x, sc[0], sh[0]), 0.0f);
        v.y = fmaxf(fmaf(v.y, sc[1], sh[1]), 0.0f);
        v.z = fmaxf(fmaf(v.z, sc[2], sh[2]), 0.0f);
        v.w = fmaxf(fmaf(v.w, sc[3], sh[3]), 0.0f);
        ((float4*)xout)[i] = v;
    }
}

// ---------------------------------------------------------------------------
extern "C" void kernel_launch(void* const* d_in, const int* in_sizes, int n_in,
                              void* d_out, int out_size, void* d_ws, size_t ws_size,
                              hipStream_t stream)
{
    const float* x0    = (const float*)d_in[0];
    const int*   eidx  = (const int*)d_in[1];
    const float* eattr = (const float*)d_in[2];
    const float* We    = (const float*)d_in[3];
    const float* be    = (const float*)d_in[4];
    const float* W1    = (const float*)d_in[5];
    const float* b1    = (const float*)d_in[6];
    const float* W2    = (const float*)d_in[7];
    const float* b2    = (const float*)d_in[8];
    const float* gamma = (const float*)d_in[9];
    const float* beta  = (const float*)d_in[10];
    const float* Wout  = (const float*)d_in[11];
    const float* bout  = (const float*)d_in[12];
    float* out = (float*)d_out;

    const int* src = eidx;
    const int* dst = eidx + N_EDGES;

    const size_t NH = (size_t)N_NODES * HID;

    // workspace layout (fp32/int32 elements)
    float* A     = (float*)d_ws;                 // post-layer x        (NH)
    float* AGG   = A + NH;                       // segmented sums      (NH)
    float* stats = AGG + NH;                     // 128 floats
    int* cnt      = (int*)(stats + 128);         // N_NODES
    int* bsum     = cnt + N_NODES;               // NB_SCAN (pad 128)
    int* bofs     = bsum + 128;                  // NB_SCAN (pad 128)
    int* row_ptr  = bofs + 128;                  // N_NODES + 1
    int* pos      = row_ptr + N_NODES + 1;       // N_NODES
    int* perm_e   = pos + N_NODES;               // N_EDGES
    int* perm_src = perm_e + N_EDGES;            // N_EDGES
    float* B = out;                              // pre-BN MLP output (reuse d_out)

    // ---- build CSR-by-dst (once; shared by all 3 layers) ----
    hipMemsetAsync(cnt, 0, N_NODES * sizeof(int), stream);
    hist_kernel<<<1024, 256, 0, stream>>>(dst, cnt);
    scan1_kernel<<<NB_SCAN, 256, 0, stream>>>(cnt, bsum);
    scan2_kernel<<<1, 128, 0, stream>>>(bsum, bofs, row_ptr);
    scan3_kernel<<<NB_SCAN, 256, 0, stream>>>(cnt, bofs, row_ptr, pos);
    scatter_kernel<<<1024, 256, 0, stream>>>(src, dst, pos, perm_e, perm_src);

    const int mlp_blocks    = ((N_NODES + 63) / 64 + 3) / 4;           // 391
    const int gather_blocks = (N_NODES + G_NODES - 1) / G_NODES;       // 6250

    const float* xin = x0;
    for (int i = 0; i < 3; ++i) {
        hipMemsetAsync(stats, 0, 128 * sizeof(float), stream);

        gather_csr_kernel<<<gather_blocks, 256, 0, stream>>>(
            xin, eattr, row_ptr, perm_e, perm_src,
            We + (size_t)i * EDIM * HID, be + (size_t)i * HID, AGG);

        mlp_kernel<<<mlp_blocks, 256, 0, stream>>>(
            xin, AGG,
            W1 + (size_t)i * HID * HID, b1 + (size_t)i * HID,
            W2 + (size_t)i * HID * HID, b2 + (size_t)i * HID, B);

        stats_kernel<<<256, 256, 0, stream>>>(B, stats);

        bn_relu_kernel<<<1024, 256, 0, stream>>>(
            B, stats, gamma + (size_t)i * HID, beta + (size_t)i * HID, A);

        xin = A;
    }

    out_kernel<<<mlp_blocks, 256, 0, stream>>>(A, Wout, bout, out);
}

// Round 4
// 1477.115 us; speedup vs baseline: 1.0951x; 1.0951x over previous
//
#include <hip/hip_runtime.h>
#include <stdint.h>

#define N_NODES 100000
#define N_EDGES 1600000
#define HID 64
#define EDIM 32
#define BN_EPS 1e-5f

#define SCAN_CHUNK 1024
#define NB_SCAN ((N_NODES + SCAN_CHUNK - 1) / SCAN_CHUNK)   // 98

#define G_NODES 16                       // dst nodes per block (gather)

// ---------------------------------------------------------------------------
// Counting sort of edges by dst.  Built once per call, reused by all 3 layers.
// ---------------------------------------------------------------------------
__global__ __launch_bounds__(256) void hist_kernel(
    const int* __restrict__ dst, int* __restrict__ cnt)
{
    int i = (int)(blockIdx.x * blockDim.x + threadIdx.x);
    const int stride = (int)(gridDim.x * blockDim.x);
    for (; i < N_EDGES; i += stride) atomicAdd(&cnt[dst[i]], 1);
}

__global__ __launch_bounds__(256) void scan1_kernel(
    const int* __restrict__ cnt, int* __restrict__ bsum)
{
    __shared__ int s[256];
    const int b = (int)blockIdx.x, t = (int)threadIdx.x;
    const int base = b * SCAN_CHUNK + t * 4;
    int sum = 0;
#pragma unroll
    for (int k = 0; k < 4; ++k) {
        int idx = base + k;
        if (idx < N_NODES) sum += cnt[idx];
    }
    s[t] = sum;
    __syncthreads();
    for (int off = 128; off > 0; off >>= 1) {
        if (t < off) s[t] += s[t + off];
        __syncthreads();
    }
    if (t == 0) bsum[b] = s[0];
}

__global__ __launch_bounds__(128) void scan2_kernel(
    const int* __restrict__ bsum, int* __restrict__ bofs, int* __restrict__ row_ptr)
{
    __shared__ int s[128];
    const int t = (int)threadIdx.x;
    const int v = (t < NB_SCAN) ? bsum[t] : 0;
    s[t] = v;
    __syncthreads();
    for (int off = 1; off < 128; off <<= 1) {
        int add = (t >= off) ? s[t - off] : 0;
        __syncthreads();
        s[t] += add;
        __syncthreads();
    }
    if (t < NB_SCAN) bofs[t] = s[t] - v;
    if (t == NB_SCAN - 1) row_ptr[N_NODES] = s[t];
}

__global__ __launch_bounds__(256) void scan3_kernel(
    const int* __restrict__ cnt, const int* __restrict__ bofs,
    int* __restrict__ row_ptr, int* __restrict__ pos)
{
    __shared__ int s[256];
    const int b = (int)blockIdx.x, t = (int)threadIdx.x;
    const int base = b * SCAN_CHUNK + t * 4;
    int v[4];
    int sum = 0;
#pragma unroll
    for (int k = 0; k < 4; ++k) {
        int idx = base + k;
        v[k] = (idx < N_NODES) ? cnt[idx] : 0;
        sum += v[k];
    }
    s[t] = sum;
    __syncthreads();
    for (int off = 1; off < 256; off <<= 1) {
        int add = (t >= off) ? s[t - off] : 0;
        __syncthreads();
        s[t] += add;
        __syncthreads();
    }
    int run = s[t] - sum + bofs[b];
#pragma unroll
    for (int k = 0; k < 4; ++k) {
        int idx = base + k;
        if (idx < N_NODES) {
            row_ptr[idx] = run;
            pos[idx] = run;
            run += v[k];
        }
    }
}

__global__ __launch_bounds__(256) void scatter_kernel(
    const int* __restrict__ src, const int* __restrict__ dst,
    int* __restrict__ pos, int* __restrict__ perm_e, int* __restrict__ perm_src)
{
    int i = (int)(blockIdx.x * blockDim.x + threadIdx.x);
    const int stride = (int)(gridDim.x * blockDim.x);
    for (; i < N_EDGES; i += stride) {
        const int d = dst[i];
        const int p = atomicAdd(&pos[d], 1);
        perm_e[p] = i;
        perm_src[p] = src[i];
    }
}

// ---------------------------------------------------------------------------
// One-time gather-copy of edge attributes into CSR (dst-sorted) order.
// Turns all 3 layers' attr access into a linear stream.
// ---------------------------------------------------------------------------
__global__ __launch_bounds__(256) void permute_attr_kernel(
    const float* __restrict__ eattr, const int* __restrict__ perm_e,
    float* __restrict__ outp)
{
    const int total = N_EDGES * 8;                    // float4 units
    int i = (int)(blockIdx.x * blockDim.x + threadIdx.x);
    const int stride = (int)(gridDim.x * blockDim.x);
    for (; i < total; i += stride) {
        const int row = i >> 3, part = i & 7;
        ((float4*)outp)[i] =
            ((const float4*)eattr)[(size_t)(unsigned)perm_e[row] * 8 + part];
    }
}

// ---------------------------------------------------------------------------
// Gather over CSR ranges.  LINEAR=true: attr is pre-permuted, row j of attr
// is a wave-uniform linear address (one L2 line per edge, broadcast to all
// lanes).  A per-lane touch of rows gb+64..gb+127 (one VMEM instruction = 64
// line fetches) warms the next 64-edge group one group (~5k cy) ahead, so the
// uniform row loads hit L2.  Per-node sums come from running-sum snapshots at
// the 3 interior row_ptr boundaries.  No LDS, no barriers, no atomics.
// LINEAR=false: fallback via perm_e indirection (workspace too small).
// ---------------------------------------------------------------------------
template<bool LINEAR>
__global__ __launch_bounds__(256, 4) void gather_kernel(
    const float* __restrict__ x, const float* __restrict__ attr,
    const int* __restrict__ row_ptr, const int* __restrict__ perm_e,
    const int* __restrict__ perm_src,
    const float* __restrict__ We, const float* __restrict__ be,
    float* __restrict__ agg)
{
    const int tid  = (int)threadIdx.x;
    const int lane = tid & 63;
    const int w    = __builtin_amdgcn_readfirstlane(tid >> 6);   // wave 0..3
    const int node_lo = (int)blockIdx.x * G_NODES + 4 * w;

    // this wave's 4 node ranges (forced into SGPRs)
    int rpv[5];
#pragma unroll
    for (int i = 0; i < 5; ++i) {
        int n = node_lo + i;
        n = (n < N_NODES) ? n : N_NODES;
        rpv[i] = __builtin_amdgcn_readfirstlane(row_ptr[n]);
    }
    const int F0 = rpv[0], rp1 = rpv[1], rp2 = rpv[2], rp3 = rpv[3], F1 = rpv[4];

    float a = 0.0f, sn1 = 0.0f, sn2 = 0.0f, sn3 = 0.0f;

    if (F0 < F1) {
        const int FL = F1 - 1;

        // ---- group-0 L2 warm: issue before anything else ------------------
        float pf_prev;
        {
            int gl = F0 + lane; if (gl > FL) gl = FL;
            size_t row = LINEAR ? (size_t)gl : (size_t)(unsigned)perm_e[gl];
            pf_prev = attr[row * EDIM];
        }

        // this lane's weight column (reused for all edges of the wave)
        float wv[EDIM];
#pragma unroll
        for (int k = 0; k < EDIM; ++k) wv[k] = We[k * HID + lane];
        const float bias = be[lane];

        // ---- prime the x-gather pipeline (depth 2) ------------------------
        int jA = F0;
        int jB = F0 + 1; if (jB > FL) jB = FL;
        int jC = F0 + 2; if (jC > FL) jC = FL;
        const int s0 = perm_src[jA];
        const int s1 = perm_src[jB];
        int sN = perm_src[jC];
        float xq0 = x[(size_t)(unsigned)s0 * HID + lane];
        float xq1 = x[(size_t)(unsigned)s1 * HID + lane];

        for (int gb = F0; gb < F1; gb += 64) {
            const int gend = (gb + 64 < F1) ? gb + 64 : F1;

            // ---- warm the NEXT 64-edge group (64 lines in one instruction)
            float pf = 0.0f;
            if (gb + 64 < F1) {
                int gl = gb + 64 + lane; if (gl > FL) gl = FL;
                size_t row = LINEAR ? (size_t)gl : (size_t)(unsigned)perm_e[gl];
                pf = attr[row * EDIM];
            }

#pragma unroll 2
            for (int j = gb; j < gend; ++j) {
                // per-lane x prefetch for edge j+2
                const float xq2 = x[(size_t)(unsigned)sN * HID + lane];
                int j3 = j + 3; if (j3 > FL) j3 = FL;
                sN = perm_src[j3];

                size_t row = LINEAR ? (size_t)j : (size_t)(unsigned)perm_e[j];
                const float4* ap = (const float4*)(attr + row * EDIM);

                // e = bias + attr . We_col, 4 independent FMA chains
                float e0 = bias, e1 = 0.0f, e2 = 0.0f, e3 = 0.0f;
#pragma unroll
                for (int k = 0; k < 8; ++k) {
                    const float4 q = ap[k];
                    e0 = fmaf(q.x, wv[4 * k + 0], e0);
                    e1 = fmaf(q.y, wv[4 * k + 1], e1);
                    e2 = fmaf(q.z, wv[4 * k + 2], e2);
                    e3 = fmaf(q.w, wv[4 * k + 3], e3);
                }
                a += fmaxf(xq0 + ((e0 + e1) + (e2 + e3)), 0.0f);
                xq0 = xq1; xq1 = xq2;

                // running-sum snapshots at node boundaries (uniform compares)
                if (j + 1 == rp1) sn1 = a;
                if (j + 1 == rp2) sn2 = a;
                if (j + 1 == rp3) sn3 = a;
            }

            // keep previous group's warm loads live (arrived long ago)
            asm volatile("" :: "v"(pf_prev));
            pf_prev = pf;
        }
        asm volatile("" :: "v"(pf_prev));
    }

    // segment sums from running-sum snapshots
    float r[4];
    r[0] = sn1;
    r[1] = sn2 - sn1;
    r[2] = sn3 - sn2;
    r[3] = a - sn3;
#pragma unroll
    for (int q = 0; q < 4; ++q) {
        const int n = node_lo + q;
        if (n < N_NODES) agg[(size_t)n * HID + lane] = r[q];
    }
}

// ---------------------------------------------------------------------------
// MLP kernel: lane = node.  u = relu((x+agg)@W1+b1)@W2+b2
// ---------------------------------------------------------------------------
__global__ __launch_bounds__(256) void mlp_kernel(
    const float* __restrict__ xin, const float* __restrict__ agg,
    const float* __restrict__ W1, const float* __restrict__ b1,
    const float* __restrict__ W2, const float* __restrict__ b2,
    float* __restrict__ uout)
{
    const int lane = threadIdx.x & 63;
    const int wid  = (int)((blockIdx.x * blockDim.x + threadIdx.x) >> 6);
    const int n    = wid * 64 + lane;
    const bool ok  = (n < N_NODES);
    const size_t base = (size_t)n * HID;

    float h[HID];
    if (ok) {
        const float4* px = (const float4*)(xin + base);
        const float4* pa = (const float4*)(agg + base);
#pragma unroll
        for (int j = 0; j < HID / 4; ++j) {
            float4 xv = px[j];
            float4 av = pa[j];
            h[4 * j + 0] = xv.x + av.x;
            h[4 * j + 1] = xv.y + av.y;
            h[4 * j + 2] = xv.z + av.z;
            h[4 * j + 3] = xv.w + av.w;
        }
    } else {
#pragma unroll
        for (int k = 0; k < HID; ++k) h[k] = 0.0f;
    }

    float u[HID];
#pragma unroll
    for (int f = 0; f < HID; ++f) u[f] = b2[f];

    for (int c = 0; c < 4; ++c) {
        float t[16];
#pragma unroll
        for (int j = 0; j < 16; ++j) t[j] = b1[c * 16 + j];
#pragma unroll
        for (int k = 0; k < HID; ++k) {
            const float hk = h[k];
#pragma unroll
            for (int j = 0; j < 16; ++j)
                t[j] = fmaf(hk, W1[k * HID + c * 16 + j], t[j]);
        }
#pragma unroll
        for (int j = 0; j < 16; ++j) t[j] = fmaxf(t[j], 0.0f);
#pragma unroll
        for (int j = 0; j < 16; ++j) {
            const float tj = t[j];
#pragma unroll
            for (int f = 0; f < HID; ++f)
                u[f] = fmaf(tj, W2[(c * 16 + j) * HID + f], u[f]);
        }
    }

    if (ok) {
        float4* po = (float4*)(uout + base);
#pragma unroll
        for (int j = 0; j < HID / 4; ++j)
            po[j] = make_float4(u[4 * j], u[4 * j + 1], u[4 * j + 2], u[4 * j + 3]);
    }
}

// ---------------------------------------------------------------------------
// Final projection: out = x @ Wout + bout
// ---------------------------------------------------------------------------
__global__ __launch_bounds__(256) void out_kernel(
    const float* __restrict__ xin, const float* __restrict__ Wo,
    const float* __restrict__ bo, float* __restrict__ out)
{
    const int lane = threadIdx.x & 63;
    const int wid  = (int)((blockIdx.x * blockDim.x + threadIdx.x) >> 6);
    const int n    = wid * 64 + lane;
    const bool ok  = (n < N_NODES);
    const size_t base = (size_t)n * HID;

    float h[HID];
    if (ok) {
        const float4* px = (const float4*)(xin + base);
#pragma unroll
        for (int j = 0; j < HID / 4; ++j) {
            float4 xv = px[j];
            h[4 * j + 0] = xv.x; h[4 * j + 1] = xv.y;
            h[4 * j + 2] = xv.z; h[4 * j + 3] = xv.w;
        }
    } else {
#pragma unroll
        for (int k = 0; k < HID; ++k) h[k] = 0.0f;
    }

    for (int c = 0; c < 4; ++c) {
        float t[16];
#pragma unroll
        for (int j = 0; j < 16; ++j) t[j] = bo[c * 16 + j];
#pragma unroll
        for (int k = 0; k < HID; ++k) {
            const float hk = h[k];
#pragma unroll
            for (int j = 0; j < 16; ++j)
                t[j] = fmaf(hk, Wo[k * HID + c * 16 + j], t[j]);
        }
        if (ok) {
            float4* po = (float4*)(out + base + c * 16);
#pragma unroll
            for (int j = 0; j < 4; ++j)
                po[j] = make_float4(t[4 * j], t[4 * j + 1], t[4 * j + 2], t[4 * j + 3]);
        }
    }
}

// ---------------------------------------------------------------------------
// BN statistics (sum / sumsq per feature)
// ---------------------------------------------------------------------------
__global__ __launch_bounds__(256) void stats_kernel(
    const float* __restrict__ u, float* __restrict__ stats)
{
    __shared__ float ls[256];
    __shared__ float ls2[256];
    const int tid = (int)threadIdx.x;
    const int g   = (int)(blockIdx.x * 256 + tid);
    const int f   = g & 63;
    const int row = g >> 6;
    const int rstride = (int)((gridDim.x * 256) >> 6);

    float s = 0.0f, s2 = 0.0f;
    for (int n = row; n < N_NODES; n += rstride) {
        float v = u[(size_t)n * HID + f];
        s += v;
        s2 = fmaf(v, v, s2);
    }
    ls[tid] = s;
    ls2[tid] = s2;
    __syncthreads();
    if (tid < 64) {
        float a = ls[tid] + ls[tid + 64] + ls[tid + 128] + ls[tid + 192];
        float b = ls2[tid] + ls2[tid + 64] + ls2[tid + 128] + ls2[tid + 192];
        atomicAdd(&stats[tid], a);
        atomicAdd(&stats[64 + tid], b);
    }
}

// ---------------------------------------------------------------------------
// BN apply + relu
// ---------------------------------------------------------------------------
__global__ __launch_bounds__(256) void bn_relu_kernel(
    const float* __restrict__ u, const float* __restrict__ stats,
    const float* __restrict__ gamma, const float* __restrict__ beta,
    float* __restrict__ xout)
{
    const int total4 = N_NODES * HID / 4;
    int i = (int)(blockIdx.x * blockDim.x + threadIdx.x);
    const int stride = (int)(gridDim.x * blockDim.x);
    const int fb = (i * 4) & 63;

    const float invN = 1.0f / (float)N_NODES;
    float sc[4], sh[4];
#pragma unroll
    for (int j = 0; j < 4; ++j) {
        float mean = stats[fb + j] * invN;
        float var  = stats[64 + fb + j] * invN - mean * mean;
        float s    = gamma[fb + j] * rsqrtf(var + BN_EPS);
        sc[j] = s;
        sh[j] = beta[fb + j] - mean * s;
    }
    for (; i < total4; i += stride) {
        float4 v = ((const float4*)u)[i];
        v.x = fmaxf(fmaf(v.x, sc[0], sh[0]), 0.0f);
        v.y = fmaxf(fmaf(v.y, sc[1], sh[1]), 0.0f);
        v.z = fmaxf(fmaf(v.z, sc[2], sh[2]), 0.0f);
        v.w = fmaxf(fmaf(v.w, sc[3], sh[3]), 0.0f);
        ((float4*)xout)[i] = v;
    }
}

// ---------------------------------------------------------------------------
extern "C" void kernel_launch(void* const* d_in, const int* in_sizes, int n_in,
                              void* d_out, int out_size, void* d_ws, size_t ws_size,
                              hipStream_t stream)
{
    const float* x0    = (const float*)d_in[0];
    const int*   eidx  = (const int*)d_in[1];
    const float* eattr = (const float*)d_in[2];
    const float* We    = (const float*)d_in[3];
    const float* be    = (const float*)d_in[4];
    const float* W1    = (const float*)d_in[5];
    const float* b1    = (const float*)d_in[6];
    const float* W2    = (const float*)d_in[7];
    const float* b2    = (const float*)d_in[8];
    const float* gamma = (const float*)d_in[9];
    const float* beta  = (const float*)d_in[10];
    const float* Wout  = (const float*)d_in[11];
    const float* bout  = (const float*)d_in[12];
    float* out = (float*)d_out;

    const int* src = eidx;
    const int* dst = eidx + N_EDGES;

    const size_t NH = (size_t)N_NODES * HID;

    // workspace layout (fp32/int32 elements)
    float* A     = (float*)d_ws;                 // post-layer x        (NH)
    float* AGG   = A + NH;                       // segmented sums      (NH)
    float* stats = AGG + NH;                     // 128 floats
    int* cnt      = (int*)(stats + 128);         // N_NODES
    int* bsum     = cnt + N_NODES;               // NB_SCAN (pad 128)
    int* bofs     = bsum + 128;                  // NB_SCAN (pad 128)
    int* row_ptr  = bofs + 128;                  // N_NODES + 1
    int* pos      = row_ptr + N_NODES + 1;       // N_NODES
    int* perm_e   = pos + N_NODES;               // N_EDGES
    int* perm_src = perm_e + N_EDGES;            // N_EDGES
    float* B = out;                              // pre-BN MLP output (reuse d_out)

    // optional CSR-ordered attr copy (256B-aligned, at the end of the ws)
    uintptr_t eap_off = (((uintptr_t)(perm_src + N_EDGES) - (uintptr_t)d_ws)
                         + 255) & ~(uintptr_t)255;
    const size_t need = (size_t)eap_off + (size_t)N_EDGES * EDIM * sizeof(float);
    const bool lin = (ws_size >= need);
    float* EAP = (float*)((char*)d_ws + eap_off);

    // ---- build CSR-by-dst (once; shared by all 3 layers) ----
    hipMemsetAsync(cnt, 0, N_NODES * sizeof(int), stream);
    hist_kernel<<<1024, 256, 0, stream>>>(dst, cnt);
    scan1_kernel<<<NB_SCAN, 256, 0, stream>>>(cnt, bsum);
    scan2_kernel<<<1, 128, 0, stream>>>(bsum, bofs, row_ptr);
    scan3_kernel<<<NB_SCAN, 256, 0, stream>>>(cnt, bofs, row_ptr, pos);
    scatter_kernel<<<1024, 256, 0, stream>>>(src, dst, pos, perm_e, perm_src);
    if (lin)
        permute_attr_kernel<<<2048, 256, 0, stream>>>(eattr, perm_e, EAP);

    const int mlp_blocks    = ((N_NODES + 63) / 64 + 3) / 4;           // 391
    const int gather_blocks = (N_NODES + G_NODES - 1) / G_NODES;       // 6250

    const float* xin = x0;
    for (int i = 0; i < 3; ++i) {
        hipMemsetAsync(stats, 0, 128 * sizeof(float), stream);

        if (lin)
            gather_kernel<true><<<gather_blocks, 256, 0, stream>>>(
                xin, EAP, row_ptr, perm_e, perm_src,
                We + (size_t)i * EDIM * HID, be + (size_t)i * HID, AGG);
        else
            gather_kernel<false><<<gather_blocks, 256, 0, stream>>>(
                xin, eattr, row_ptr, perm_e, perm_src,
                We + (size_t)i * EDIM * HID, be + (size_t)i * HID, AGG);

        mlp_kernel<<<mlp_blocks, 256, 0, stream>>>(
            xin, AGG,
            W1 + (size_t)i * HID * HID, b1 + (size_t)i * HID,
            W2 + (size_t)i * HID * HID, b2 + (size_t)i * HID, B);

        stats_kernel<<<256, 256, 0, stream>>>(B, stats);

        bn_relu_kernel<<<1024, 256, 0, stream>>>(
            B, stats, gamma + (size_t)i * HID, beta + (size_t)i * HID, A);

        xin = A;
    }

    out_kernel<<<mlp_blocks, 256, 0, stream>>>(A, Wout, bout, out);
}